// Round 5
// baseline (531.761 us; speedup 1.0000x reference)
//
#include <hip/hip_runtime.h>

#define DEVI __device__ __forceinline__

typedef __attribute__((ext_vector_type(8))) short short8;
typedef __attribute__((ext_vector_type(4))) float f32x4;
typedef unsigned short u16;
typedef unsigned int u32;

DEVI float b2f(u16 u) { u32 x = ((u32)u) << 16; return __builtin_bit_cast(float, x); }
DEVI u16 f2b(float f) {
    u32 u = __builtin_bit_cast(u32, f);
    u32 r = u + 0x7FFFu + ((u >> 16) & 1u);   // RNE
    return (u16)(r >> 16);
}
// fast ELU: exp(v)-1 instead of expm1f; abs err ~1e-7, fine for bf16 pipeline
DEVI float eluf(float v) { return v > 0.f ? v : __expf(v) - 1.f; }

DEVI void gl16(const void* g, void* l) {
    __builtin_amdgcn_global_load_lds(
        (const __attribute__((address_space(1))) u32*)g,
        (__attribute__((address_space(3))) u32*)l, 16, 0, 0);
}

// ---------------- elementwise fp32 -> bf16 ----------------
__global__ void k_convert(const float* __restrict__ in, u16* __restrict__ out, int n) {
    int i = blockIdx.x * blockDim.x + threadIdx.x;
    int stride = gridDim.x * blockDim.x;
    for (int j = i; j * 8 < n; j += stride) {
        int base = j * 8;
        if (base + 8 <= n) {
            float4 a = *(const float4*)(in + base);
            float4 b = *(const float4*)(in + base + 4);
            short8 o;
            o[0] = (short)f2b(a.x); o[1] = (short)f2b(a.y);
            o[2] = (short)f2b(a.z); o[3] = (short)f2b(a.w);
            o[4] = (short)f2b(b.x); o[5] = (short)f2b(b.y);
            o[6] = (short)f2b(b.z); o[7] = (short)f2b(b.w);
            *(short8*)(out + base) = o;
        } else {
            for (int t = base; t < n; ++t) out[t] = f2b(in[t]);
        }
    }
}

// ---------------- build WcT (512 x 128) from w_m1a ----------------
__global__ void k_wct(const float* __restrict__ w, u16* __restrict__ wct) {
    int t = blockIdx.x * 256 + threadIdx.x;
    if (t >= 512 * 128) return;
    int k = t & 127, j = t >> 7;
    float v;
    if (j < 256) v = w[k * 256 + j] + w[(k + 128) * 256 + j];
    else { int jj = j - 256; v = w[(k + 256) * 256 + jj] + w[(k + 384) * 256 + jj]; }
    wct[j * 128 + k] = f2b(v);
}

// ---------------- transpose-convert: W (K x N fp32) -> WT (Nalloc x K bf16) ----------------
__global__ void k_tc(const float* __restrict__ w, u16* __restrict__ wt,
                     int K, int N, int Nalloc) {
    __shared__ float tile[32][33];
    int tx = threadIdx.x, ty = threadIdx.y;
    int k0 = blockIdx.y * 32, n0 = blockIdx.x * 32;
#pragma unroll
    for (int yy = 0; yy < 4; ++yy) {
        int k = k0 + ty + yy * 8, n = n0 + tx;
        tile[ty + yy * 8][tx] = (k < K && n < N) ? w[(size_t)k * N + n] : 0.f;
    }
    __syncthreads();
#pragma unroll
    for (int yy = 0; yy < 4; ++yy) {
        int n = n0 + ty + yy * 8, k = k0 + tx;
        if (n < Nalloc && k < K) wt[(size_t)n * K + k] = f2b(tile[tx][ty + yy * 8]);
    }
}

// ---------------- counting sort of edges by dst ----------------
__global__ void k_hist(const int* __restrict__ ei, int* __restrict__ hist, int E) {
    int i = blockIdx.x * 256 + threadIdx.x;
    if (i < E) atomicAdd(&hist[ei[E + i]], 1);
}

__global__ void k_scan(const int* __restrict__ hist, int* __restrict__ cursor, int NB) {
    __shared__ int part[256];
    int t = threadIdx.x;
    int base = t * 40;
    int s = 0;
    for (int i = 0; i < 40; ++i) { int idx = base + i; if (idx < NB) s += hist[idx]; }
    part[t] = s;
    __syncthreads();
    if (t == 0) { int run = 0; for (int i = 0; i < 256; ++i) { int x = part[i]; part[i] = run; run += x; } }
    __syncthreads();
    int run = part[t];
    for (int i = 0; i < 40; ++i) {
        int idx = base + i;
        if (idx < NB) { int h = hist[idx]; cursor[idx] = run; run += h; }
    }
}

__global__ void k_scatter(const int* __restrict__ ei, int* __restrict__ cursor,
                          int* __restrict__ sdst, int* __restrict__ ssrc, int E) {
    int i = blockIdx.x * 256 + threadIdx.x;
    if (i >= E) return;
    int d = ei[E + i], s = ei[i];
    int pos = atomicAdd(&cursor[d], 1);
    sdst[pos] = d;
    ssrc[pos] = s;
}

// ---------------- generic bf16 GEMM (128x128): C = epi(A @ BT^T + bias) ----------------
// EPI: 0 none->bf16, 1 ELU->bf16, 2 ReLU->bf16
template <int EPI>
__global__ __launch_bounds__(256, 2)
void k_gemm(const u16* __restrict__ A, const u16* __restrict__ BT,
            const float* __restrict__ bias, void* __restrict__ Cv,
            int M, int N, int K, int lda, int ldbt, int ldc) {
    __shared__ short lsA[128 * 64];
    __shared__ short lsB[128 * 64];
    const int tid = threadIdx.x, wave = tid >> 6, lane = tid & 63;
    const int bx = blockIdx.x, by = blockIdx.y;
    const int m0 = by * 128, n0 = bx * 128;
    const int wm = wave >> 1, wn = wave & 1;
    const int rowA = lane >> 3, colA = (lane & 7) * 8;

    f32x4 acc[4][4] = {};

    const int kch = K >> 6;
    for (int kc = 0; kc < kch; ++kc) {
#pragma unroll
        for (int i = 0; i < 4; ++i) {
            int slot = wave * 4 + i;
            const u16* ga = A + (size_t)(m0 + slot * 8 + rowA) * lda + kc * 64 + colA;
            gl16(ga, &lsA[slot * 512]);
            const u16* gb = BT + (size_t)(n0 + slot * 8 + rowA) * ldbt + kc * 64 + colA;
            gl16(gb, &lsB[slot * 512]);
        }
        __syncthreads();
#pragma unroll
        for (int ks = 0; ks < 2; ++ks) {
            short8 a[4], b[4];
#pragma unroll
            for (int m = 0; m < 4; ++m)
                a[m] = *(const short8*)&lsA[(wm * 64 + m * 16 + (lane & 15)) * 64 + ks * 32 + (lane >> 4) * 8];
#pragma unroll
            for (int n = 0; n < 4; ++n)
                b[n] = *(const short8*)&lsB[(wn * 64 + n * 16 + (lane & 15)) * 64 + ks * 32 + (lane >> 4) * 8];
#pragma unroll
            for (int m = 0; m < 4; ++m)
#pragma unroll
                for (int n = 0; n < 4; ++n)
                    acc[m][n] = __builtin_amdgcn_mfma_f32_16x16x32_bf16(a[m], b[n], acc[m][n], 0, 0, 0);
        }
        __syncthreads();
    }

#pragma unroll
    for (int m = 0; m < 4; ++m) {
#pragma unroll
        for (int n = 0; n < 4; ++n) {
            int colg = n0 + wn * 64 + n * 16 + (lane & 15);
#pragma unroll
            for (int j = 0; j < 4; ++j) {
                int rowg = m0 + wm * 64 + m * 16 + (lane >> 4) * 4 + j;
                if (rowg < M && colg < N) {
                    float v = acc[m][n][j];
                    if (bias) v += bias[colg];
                    if (EPI == 1) v = eluf(v);
                    if (EPI == 2) v = v > 0.f ? v : 0.f;
                    ((u16*)Cv)[(size_t)rowg * ldc + colg] = f2b(v);
                }
            }
        }
    }
}

// ---------------- final GEMM v2: 256x256 tile, 8 waves (2x4), double-buffered ----------------
// T3-minimum pipeline: STAGE(next) issued before compute(cur), one barrier/tile.
// T2 swizzle (linear gl16 dest + inverse-swizzled source + XOR'd reads).
// Operand-swapped MFMA -> lane holds 4 consecutive cols -> dwordx4 sigmoid stores.
// Bijective chunked XCD swizzle (grid % 8 == 0).
__global__ __launch_bounds__(512, 2)
void k_gemm2(const u16* __restrict__ A, const u16* __restrict__ BT,
             const float* __restrict__ bias, float* __restrict__ C,
             int M, int N, int K, int lda, int ldbt, int ldc, int NBX) {
    __shared__ short lsA[2][256 * 64];   // 2 x 32KB
    __shared__ short lsB[2][256 * 64];   // 2 x 32KB  (128KB total, 1 block/CU)
    const int tid = threadIdx.x, wave = tid >> 6, lane = tid & 63;
    const int g = lane >> 4, l15 = lane & 15;
    const int nb = gridDim.x, orig = blockIdx.x;
    const int cpx = nb >> 3;                      // grid divisible by 8
    const int wg = (orig & 7) * cpx + (orig >> 3);
    const int bx = wg % NBX, by = wg / NBX;
    const int m0 = by * 256, n0 = bx * 256;
    const int wm = wave >> 2, wn = wave & 3;      // 2 x 4 wave grid
    const int sr = lane >> 3, sc = lane & 7;

    auto stage = [&](int buf, int kc) {
#pragma unroll
        for (int i = 0; i < 4; ++i) {
            int s = wave * 4 + i;                 // 32 slots x 8 rows
            int br = s * 8 + sr;
            const u16* ga = A + (size_t)(m0 + br) * lda + kc * 64 + ((sc ^ (br & 7)) * 8);
            gl16(ga, &lsA[buf][s * 512]);
        }
#pragma unroll
        for (int i = 0; i < 4; ++i) {
            int s = wave * 4 + i;
            int br = s * 8 + sr;
            const u16* gb = BT + (size_t)(n0 + br) * ldbt + kc * 64 + ((sc ^ (br & 7)) * 8);
            gl16(gb, &lsB[buf][s * 512]);
        }
    };

    f32x4 acc[8][4] = {};
    const int kch = K >> 6;                       // 6
    stage(0, 0);
    __syncthreads();
    int cur = 0;
    for (int kc = 0; kc < kch; ++kc) {
        if (kc + 1 < kch) stage(cur ^ 1, kc + 1);   // loads in flight during MFMA
#pragma unroll
        for (int ks = 0; ks < 2; ++ks) {
            short8 b[4];
#pragma unroll
            for (int n = 0; n < 4; ++n) {
                int br = wn * 64 + n * 16 + l15;
                b[n] = *(const short8*)&lsB[cur][(br * 8 + ((ks * 4 + g) ^ (br & 7))) * 8];
            }
#pragma unroll
            for (int mh = 0; mh < 2; ++mh) {
                short8 a[4];
#pragma unroll
                for (int mi = 0; mi < 4; ++mi) {
                    int ar = wm * 128 + (mh * 4 + mi) * 16 + l15;
                    a[mi] = *(const short8*)&lsA[cur][(ar * 8 + ((ks * 4 + g) ^ (ar & 7))) * 8];
                }
#pragma unroll
                for (int mi = 0; mi < 4; ++mi)
#pragma unroll
                    for (int n = 0; n < 4; ++n)
                        acc[mh * 4 + mi][n] = __builtin_amdgcn_mfma_f32_16x16x32_bf16(
                            b[n], a[mi], acc[mh * 4 + mi][n], 0, 0, 0);
            }
        }
        __syncthreads();                           // drains next-tile vmcnt + lds reads
        cur ^= 1;
    }

#pragma unroll
    for (int m = 0; m < 8; ++m) {
        int row = m0 + wm * 128 + m * 16 + l15;
        if (row < M) {
#pragma unroll
            for (int n = 0; n < 4; ++n) {
                int col0 = n0 + wn * 64 + n * 16 + g * 4;
                if (col0 < N) {                    // N % 4 == 0 -> full float4 in-bounds
                    float4 bv = *(const float4*)(bias + col0);
                    float4 o;
                    o.x = 1.f / (1.f + __expf(-(acc[m][n][0] + bv.x)));
                    o.y = 1.f / (1.f + __expf(-(acc[m][n][1] + bv.y)));
                    o.z = 1.f / (1.f + __expf(-(acc[m][n][2] + bv.z)));
                    o.w = 1.f / (1.f + __expf(-(acc[m][n][3] + bv.w)));
                    *(float4*)(C + (size_t)row * ldc + col0) = o;
                }
            }
        }
    }
}

// ---------------- edge kernel v4: sorted edges + reg-pipelined gather (T14) ----------------
__global__ __launch_bounds__(256, 2)
void k_edge(const u16* __restrict__ P, const int* __restrict__ sdst,
            const int* __restrict__ ssrc, const float* __restrict__ b1,
            const u16* __restrict__ W2T, const float* __restrict__ b2,
            float* __restrict__ agg) {
    __shared__ __align__(16) char smem[49152];   // A:[0,16K) B:[16K,48K) O:[0,34816)
    __shared__ int dstl[128];
    __shared__ int srcl[128];
    short* lsA = (short*)smem;
    short* lsB = (short*)(smem + 16384);
    float* lsO = (float*)smem;                   // 128 x 68 fp32
    const int tid = threadIdx.x, wave = tid >> 6, lane = tid & 63;
    const int eb = blockIdx.x * 128;
    const int g = lane >> 4, l15 = lane & 15;

    if (tid < 128) srcl[tid] = ssrc[eb + tid];
    else dstl[tid - 128] = sdst[eb + (tid - 128)];
    __syncthreads();

    short8 rpd[4], rps[4];
    auto loadA = [&](int kc) {
#pragma unroll
        for (int it = 0; it < 4; ++it) {
            int chunk = it * 256 + tid;
            int r = chunk >> 3, cc = chunk & 7;
            int col = kc * 64 + cc * 8;
            rpd[it] = *(const short8*)(P + (size_t)dstl[r] * 512 + col);
            rps[it] = *(const short8*)(P + (size_t)srcl[r] * 512 + 256 + col);
        }
    };

    loadA(0);
    f32x4 acc[4][2][4] = {};

    for (int kc = 0; kc < 4; ++kc) {
        // ELU + swizzled LDS write from prefetched regs
#pragma unroll
        for (int it = 0; it < 4; ++it) {
            int chunk = it * 256 + tid;
            int r = chunk >> 3, cc = chunk & 7;
            int col = kc * 64 + cc * 8;
            float bv[8];
            *(float4*)&bv[0] = *(const float4*)(b1 + col);
            *(float4*)&bv[4] = *(const float4*)(b1 + col + 4);
            short8 o;
#pragma unroll
            for (int jj = 0; jj < 8; ++jj) {
                float v = b2f((u16)rpd[it][jj]) + b2f((u16)rps[it][jj]) + bv[jj];
                o[jj] = (short)f2b(eluf(v));
            }
            int ccs = cc ^ (r & 7);
            *(short8*)&lsA[(r * 8 + ccs) * 8] = o;
        }
        // B stage
#pragma unroll
        for (int i = 0; i < 8; ++i) {
            int br = (wave * 8 + i) * 8 + (lane >> 3);
            const u16* gb = W2T + (size_t)br * 256 + kc * 64 + (((lane & 7) ^ (br & 7)) * 8);
            gl16(gb, lsB + (wave * 8 + i) * 512);
        }
        __syncthreads();
        if (kc < 3) loadA(kc + 1);               // gather latency hides under MFMA
#pragma unroll
        for (int nq = 0; nq < 4; ++nq) {
#pragma unroll
            for (int ks = 0; ks < 2; ++ks) {
                short8 a[2], b[4];
#pragma unroll
                for (int m = 0; m < 2; ++m) {
                    int ar = wave * 32 + m * 16 + l15;
                    a[m] = *(const short8*)&lsA[(ar * 8 + ((ks * 4 + g) ^ (ar & 7))) * 8];
                }
#pragma unroll
                for (int n = 0; n < 4; ++n) {
                    int br = nq * 64 + n * 16 + l15;
                    b[n] = *(const short8*)&lsB[(br * 8 + ((ks * 4 + g) ^ (br & 7))) * 8];
                }
#pragma unroll
                for (int m = 0; m < 2; ++m)
#pragma unroll
                    for (int n = 0; n < 4; ++n)
                        acc[nq][m][n] = __builtin_amdgcn_mfma_f32_16x16x32_bf16(a[m], b[n], acc[nq][m][n], 0, 0, 0);
            }
        }
        __syncthreads();
    }

#pragma unroll
    for (int nq = 0; nq < 4; ++nq) {
        float b2v[4];
#pragma unroll
        for (int n = 0; n < 4; ++n) b2v[n] = b2[nq * 64 + n * 16 + l15];
#pragma unroll
        for (int m = 0; m < 2; ++m)
#pragma unroll
            for (int n = 0; n < 4; ++n)
#pragma unroll
                for (int j = 0; j < 4; ++j) {
                    int row = wave * 32 + m * 16 + g * 4 + j;
                    lsO[row * 68 + n * 16 + l15] = eluf(acc[nq][m][n][j] + b2v[n]);
                }
        __syncthreads();
        {
            int r0 = wave * 32;
            int dprev = dstl[r0];
            float sum = 0.f;
            for (int i = 0; i < 32; ++i) {
                int row = r0 + i;
                int d = dstl[row];
                float v = lsO[row * 68 + lane];
                if (d != dprev) {
                    atomicAdd(&agg[(size_t)dprev * 256 + nq * 64 + lane], sum);
                    sum = v; dprev = d;
                } else sum += v;
            }
            atomicAdd(&agg[(size_t)dprev * 256 + nq * 64 + lane], sum);
        }
        __syncthreads();
    }
}

extern "C" void kernel_launch(void* const* d_in, const int* in_sizes, int n_in,
                              void* d_out, int out_size, void* d_ws, size_t ws_size,
                              hipStream_t stream) {
    const float* api    = (const float*)d_in[0];
    const int*   ei     = (const int*)d_in[2];
    const float* w_m1a  = (const float*)d_in[7];
    const float* b_m1a  = (const float*)d_in[8];
    const float* w_m1b  = (const float*)d_in[9];
    const float* b_m1b  = (const float*)d_in[10];
    const float* w_m2a  = (const float*)d_in[11];
    const float* b_m2a  = (const float*)d_in[12];
    const float* w_m2b  = (const float*)d_in[13];
    const float* b_m2b  = (const float*)d_in[14];
    const float* w_ma   = (const float*)d_in[15];
    const float* b_ma   = (const float*)d_in[16];
    const float* w_mb   = (const float*)d_in[17];
    const float* b_mb   = (const float*)d_in[18];
    const float* w_inc1 = (const float*)d_in[19];
    const float* b_inc1 = (const float*)d_in[20];
    const float* w_inc2 = (const float*)d_in[21];
    const float* b_inc2 = (const float*)d_in[22];

    const int N = 10000, C = 128, E = 320000, Mp = 10112;   // Mp = 79*128
    const int Mp2 = 10240;                                   // 40*256 (final-GEMM padding)

    char* w = (char*)d_ws;
    size_t off = 0;
    auto alloc = [&](size_t bytes) { void* p = w + off; off += (bytes + 255) & ~(size_t)255; return p; };
    u16* e16   = (u16*)alloc((size_t)Mp * 128 * 2);
    u16* WcT   = (u16*)alloc(512 * 128 * 2);
    u16* P     = (u16*)alloc((size_t)Mp * 512 * 2);
    u16* w1bT  = (u16*)alloc(256 * 256 * 2);
    u16* w2aT  = (u16*)alloc(256 * 256 * 2);
    u16* w2bT  = (u16*)alloc(256 * 256 * 2);
    u16* waT   = (u16*)alloc(256 * 256 * 2);
    u16* wbT   = (u16*)alloc(256 * 256 * 2);
    u16* i1T   = (u16*)alloc(384 * 128 * 2);
    u16* i2T   = (u16*)alloc((size_t)Mp2 * 384 * 2);
    float* agg = (float*)alloc((size_t)N * 256 * 4);
    u16* agg16 = (u16*)alloc((size_t)Mp * 256 * 2);
    u16* hbA   = (u16*)alloc((size_t)Mp * 256 * 2);
    u16* hbB   = (u16*)alloc((size_t)Mp * 256 * 2);
    u16* H1    = (u16*)alloc((size_t)Mp2 * 384 * 2);
    int* hist  = (int*)alloc((size_t)N * 4);
    int* cursor= (int*)alloc((size_t)N * 4);
    int* sdst  = (int*)alloc((size_t)E * 4);
    int* ssrc  = (int*)alloc((size_t)E * 4);
    (void)ws_size; (void)in_sizes; (void)n_in; (void)out_size;

    dim3 tb(32, 8);
    // sort edges by dst (counting sort)
    hipMemsetAsync(hist, 0, (size_t)N * 4, stream);
    k_hist<<<1250, 256, 0, stream>>>(ei, hist, E);
    k_scan<<<1, 256, 0, stream>>>(hist, cursor, N);
    k_scatter<<<1250, 256, 0, stream>>>(ei, cursor, sdst, ssrc, E);

    k_convert<<<640, 256, 0, stream>>>(api, e16, N * C);
    k_wct<<<256, 256, 0, stream>>>(w_m1a, WcT);
    k_tc<<<dim3(8, 8),  tb, 0, stream>>>(w_m1b,  w1bT, 256, 256, 256);
    k_tc<<<dim3(8, 8),  tb, 0, stream>>>(w_m2a,  w2aT, 256, 256, 256);
    k_tc<<<dim3(8, 8),  tb, 0, stream>>>(w_m2b,  w2bT, 256, 256, 256);
    k_tc<<<dim3(8, 8),  tb, 0, stream>>>(w_ma,   waT,  256, 256, 256);
    k_tc<<<dim3(8, 8),  tb, 0, stream>>>(w_mb,   wbT,  256, 256, 256);
    k_tc<<<dim3(12, 4), tb, 0, stream>>>(w_inc1, i1T,  128, 384, 384);
    k_tc<<<dim3(320, 12), tb, 0, stream>>>(w_inc2, i2T, 384, 10000, Mp2);
    hipMemsetAsync(agg, 0, (size_t)N * 256 * 4, stream);

    // P = e @ Wc  (node projections [pd | ps])
    k_gemm<0><<<dim3(4, 79), 256, 0, stream>>>(e16, WcT, nullptr, P, N, 512, 128, 128, 128, 512);
    // edge layer + segment-sum (sorted, reg-pipelined)
    k_edge<<<2500, 256, 0, stream>>>(P, sdst, ssrc, b_m1a, w1bT, b_m1b, agg);
    k_convert<<<640, 256, 0, stream>>>(agg, agg16, N * 256);
    // node MLPs
    k_gemm<1><<<dim3(2, 79), 256, 0, stream>>>(agg16, w2aT, b_m2a, hbA, N, 256, 256, 256, 256, 256);
    k_gemm<1><<<dim3(2, 79), 256, 0, stream>>>(hbA,   w2bT, b_m2b, hbB, N, 256, 256, 256, 256, 256);
    k_gemm<1><<<dim3(2, 79), 256, 0, stream>>>(hbB,   waT,  b_ma,  hbA, N, 256, 256, 256, 256, 256);
    k_gemm<1><<<dim3(2, 79), 256, 0, stream>>>(hbA,   wbT,  b_mb,  hbB, N, 256, 256, 256, 256, 256);
    // h[:, -128:] @ w_inc1, ReLU
    k_gemm<2><<<dim3(3, 79), 256, 0, stream>>>(hbB + 128, i1T, b_inc1, H1, N, 384, 128, 256, 128, 384);
    // final: sigmoid(H1 @ w_inc2 + b_inc2) -> d_out fp32 (256x256 dbuf tiles, 40x40 grid)
    k_gemm2<<<40 * 40, 512, 0, stream>>>(H1, i2T, b_inc2, (float*)d_out,
                                         N, 10000, 384, 384, 384, 10000, 40);
}